// Round 3
// baseline (322.016 us; speedup 1.0000x reference)
//
#include <hip/hip_runtime.h>

#define INV_T 14.285714285714286f  // 1/0.07

typedef float f32x16 __attribute__((ext_vector_type(16)));
typedef float f32x4 __attribute__((ext_vector_type(4)));
typedef __bf16 bf16x8 __attribute__((ext_vector_type(8)));
typedef unsigned short u16x8 __attribute__((ext_vector_type(8)));

__device__ __forceinline__ unsigned short f2bf(float f) {
    unsigned int x = __float_as_uint(f);
    x += 0x7fffu + ((x >> 16) & 1u);
    return (unsigned short)(x >> 16);
}

__device__ __forceinline__ void async16(unsigned short* l, const unsigned short* g) {
    __builtin_amdgcn_global_load_lds(
        (const __attribute__((address_space(1))) unsigned int*)g,
        (__attribute__((address_space(3))) unsigned int*)l, 16, 0, 0);
}

// ---- merged: fp32->bf16 convert + per-row distance/Sp/counts ----
__global__ void __launch_bounds__(256) k_prep(const float* __restrict__ emb,
                                              const float* __restrict__ center,
                                              const int* __restrict__ labels,
                                              unsigned short* __restrict__ embB,
                                              float* __restrict__ out,
                                              float* __restrict__ Sp,
                                              int* __restrict__ cnt, int D) {
    int i = blockIdx.x;
    int tid = threadIdx.x;
    const float4* row = (const float4*)(emb + (size_t)i * D);
    const float4* c4 = (const float4*)center;
    float4 e = row[tid];
    float4 c = c4[tid];
    if (embB)
        ((ushort4*)(embB + (size_t)i * D))[tid] =
            make_ushort4(f2bf(e.x), f2bf(e.y), f2bf(e.z), f2bf(e.w));
    float dx = e.x - c.x, dy = e.y - c.y, dz = e.z - c.z, dw = e.w - c.w;
    float d2 = dx * dx + dy * dy + dz * dz + dw * dw;
    float sp = e.x * c.x + e.y * c.y + e.z * c.z + e.w * c.w;
#pragma unroll
    for (int m = 1; m <= 32; m <<= 1) {
        d2 += __shfl_xor(d2, m, 64);
        sp += __shfl_xor(sp, m, 64);
    }
    __shared__ float sd2[4], ssp[4];
    int wave = tid >> 6;
    if ((tid & 63) == 0) { sd2[wave] = d2; ssp[wave] = sp; }
    __syncthreads();
    if (tid == 0) {
        float dd = sd2[0] + sd2[1] + sd2[2] + sd2[3];
        float ss = ssp[0] + ssp[1] + ssp[2] + ssp[3];
        out[5 + i] = sqrtf(dd);
        Sp[i] = ss * INV_T;
        atomicAdd(&cnt[labels[i] == 0 ? 0 : 1], 1);
    }
}

// ---- s_m[d] = sum over machine rows of emb[:,d] ----
__global__ void __launch_bounds__(256) k_colsum(const float* __restrict__ emb,
                                                const int* __restrict__ labels,
                                                float* __restrict__ s_m, int D) {
    int t = threadIdx.x;
    int r0 = blockIdx.x * 32;
    float4 acc = {0.f, 0.f, 0.f, 0.f};
#pragma unroll 4
    for (int r = 0; r < 32; ++r) {
        float sc = (labels[r0 + r] == 0) ? 1.f : 0.f;
        float4 v = ((const float4*)(emb + (size_t)(r0 + r) * D))[t];
        acc.x += v.x * sc; acc.y += v.y * sc; acc.z += v.z * sc; acc.w += v.w * sc;
    }
    atomicAdd(&s_m[t * 4 + 0], acc.x);
    atomicAdd(&s_m[t * 4 + 1], acc.y);
    atomicAdd(&s_m[t * 4 + 2], acc.z);
    atomicAdd(&s_m[t * 4 + 3], acc.w);
}

// ---- sumexp[i] += sum_{j != i} exp((S_ij - 1)/T) ----
// 256x128 tiles over the strict upper triangle; each (i<j) pair computed once,
// scattered to BOTH row-sum i and col-sum j. 4 waves, wave tile 128x64 via
// mfma_f32_32x32x16_bf16 (4x2 frags). XOR-swizzled LDS (16B chunks).
template <bool PRE>
__global__ void __launch_bounds__(256, 2) k_sumexp(const unsigned short* __restrict__ embB,
                                                   const float* __restrict__ embF,
                                                   float* __restrict__ sumexp, int D, int nRT) {
    // decode bid -> (R, C): off(R) = R*(M-R), M = 2*nRT+1; C = 2R + (bid - off)
    int bid = blockIdx.x;
    int M = 2 * nRT + 1;
    float mf = (float)M;
    int R = (int)((mf - sqrtf(fmaxf(mf * mf - 4.0f * (float)bid, 0.f))) * 0.5f);
    if (R < 0) R = 0;
    if (R > nRT - 1) R = nRT - 1;
    while (R + 1 <= nRT - 1 && (R + 1) * (M - (R + 1)) <= bid) ++R;
    while (R > 0 && R * (M - R) > bid) --R;
    int C = 2 * R + (bid - R * (M - R));

    int rowbase = R * 256, colbase = C * 128;
    int tid = threadIdx.x;
    int wave = tid >> 6, lane = tid & 63;
    int wr = wave >> 1, wc = wave & 1;   // wave tile: rows [wr*128,+128), cols [wc*64,+64)
    int l31 = lane & 31, kk = lane >> 5; // frag: row/col = l31, k-chunk = kk*8

    __shared__ unsigned short lA[256 * 64];  // 32 KB
    __shared__ unsigned short lB[128 * 64];  // 16 KB
    __shared__ float rred[2][256];
    __shared__ float cred[2][128];

    f32x16 acc[4][2];
#pragma unroll
    for (int fr = 0; fr < 4; ++fr)
#pragma unroll
        for (int fc = 0; fc < 2; ++fc)
#pragma unroll
            for (int v = 0; v < 16; ++v) acc[fr][fc][v] = 0.f;

    const int kIters = D >> 6;
    for (int kt = 0; kt < kIters; ++kt) {
        int k0 = kt << 6;
        if constexpr (PRE) {
#pragma unroll
            for (int q = 0; q < 8; ++q) {  // lA: 2048 chunks of 16B
                int ch = q * 256 + tid;
                int row = ch >> 3, lc = ch & 7;
                int gc = lc ^ (row & 7);
                async16(&lA[ch << 3], embB + (size_t)(rowbase + row) * D + k0 + gc * 8);
            }
#pragma unroll
            for (int q = 0; q < 4; ++q) {  // lB: 1024 chunks
                int ch = q * 256 + tid;
                int row = ch >> 3, lc = ch & 7;
                int gc = lc ^ (row & 7);
                async16(&lB[ch << 3], embB + (size_t)(colbase + row) * D + k0 + gc * 8);
            }
        } else {
#pragma unroll
            for (int q = 0; q < 8; ++q) {
                int ch = q * 256 + tid;
                int row = ch >> 3, lc = ch & 7;
                int pc = lc ^ (row & 7);
                const float4* s = (const float4*)(embF + (size_t)(rowbase + row) * D + k0 + lc * 8);
                float4 a0 = s[0], a1 = s[1];
                u16x8 va = {f2bf(a0.x), f2bf(a0.y), f2bf(a0.z), f2bf(a0.w),
                            f2bf(a1.x), f2bf(a1.y), f2bf(a1.z), f2bf(a1.w)};
                *(u16x8*)&lA[(row << 6) + (pc << 3)] = va;
            }
#pragma unroll
            for (int q = 0; q < 4; ++q) {
                int ch = q * 256 + tid;
                int row = ch >> 3, lc = ch & 7;
                int pc = lc ^ (row & 7);
                const float4* s = (const float4*)(embF + (size_t)(colbase + row) * D + k0 + lc * 8);
                float4 b0 = s[0], b1 = s[1];
                u16x8 vb = {f2bf(b0.x), f2bf(b0.y), f2bf(b0.z), f2bf(b0.w),
                            f2bf(b1.x), f2bf(b1.y), f2bf(b1.z), f2bf(b1.w)};
                *(u16x8*)&lB[(row << 6) + (pc << 3)] = vb;
            }
        }
        __syncthreads();
#pragma unroll
        for (int ks = 0; ks < 4; ++ks) {   // 4 k-steps of 16
            bf16x8 bfrag[2];
#pragma unroll
            for (int fc = 0; fc < 2; ++fc) {
                int br = wc * 64 + fc * 32 + l31;
                int pc = (ks * 2 + kk) ^ (br & 7);
                bfrag[fc] = *(const bf16x8*)&lB[(br << 6) + (pc << 3)];
            }
#pragma unroll
            for (int fr = 0; fr < 4; ++fr) {
                int ar = wr * 128 + fr * 32 + l31;
                int pc = (ks * 2 + kk) ^ (ar & 7);
                bf16x8 afrag = *(const bf16x8*)&lA[(ar << 6) + (pc << 3)];
#pragma unroll
                for (int fc = 0; fc < 2; ++fc)
                    acc[fr][fc] = __builtin_amdgcn_mfma_f32_32x32x16_bf16(afrag, bfrag[fc], acc[fr][fc], 0, 0, 0);
            }
        }
        __syncthreads();
    }

    // epilogue: exp over strictly-upper elements + row/col reductions
    float rs[4][16];
    float cs[2] = {0.f, 0.f};
#pragma unroll
    for (int fr = 0; fr < 4; ++fr)
#pragma unroll
        for (int v = 0; v < 16; ++v) rs[fr][v] = 0.f;

#pragma unroll
    for (int fr = 0; fr < 4; ++fr)
#pragma unroll
        for (int fc = 0; fc < 2; ++fc) {
            int gcol = colbase + wc * 64 + fc * 32 + l31;
#pragma unroll
            for (int v = 0; v < 16; ++v) {
                int grow = rowbase + wr * 128 + fr * 32 + (v & 3) + 8 * (v >> 2) + 4 * kk;
                float e = (grow < gcol) ? __expf((acc[fr][fc][v] - 1.0f) * INV_T) : 0.f;
                rs[fr][v] += e;
                cs[fc] += e;
            }
        }

    // row sums: reduce across the 32 lanes sharing a row-group (bits 0..4)
#pragma unroll
    for (int m = 1; m <= 16; m <<= 1)
#pragma unroll
        for (int fr = 0; fr < 4; ++fr)
#pragma unroll
            for (int v = 0; v < 16; ++v) rs[fr][v] += __shfl_xor(rs[fr][v], m, 64);
    if (l31 == 0)
#pragma unroll
        for (int fr = 0; fr < 4; ++fr)
#pragma unroll
            for (int v = 0; v < 16; ++v)
                rred[wc][wr * 128 + fr * 32 + (v & 3) + 8 * (v >> 2) + 4 * kk] = rs[fr][v];

    // col sums: reduce across k-halves (bit 5)
#pragma unroll
    for (int fc = 0; fc < 2; ++fc) cs[fc] += __shfl_xor(cs[fc], 32, 64);
    if (kk == 0)
#pragma unroll
        for (int fc = 0; fc < 2; ++fc) cred[wr][wc * 64 + fc * 32 + l31] = cs[fc];

    __syncthreads();
    atomicAdd(&sumexp[rowbase + tid], rred[0][tid] + rred[1][tid]);
    if (tid < 128) atomicAdd(&sumexp[colbase + tid], cred[0][tid] + cred[1][tid]);
}

// ---- per-row finalize ----
__global__ void __launch_bounds__(256) k_finalize(const float* __restrict__ emb,
                                                  const float* __restrict__ s_m,
                                                  const float* __restrict__ Sp,
                                                  const float* __restrict__ sumexp,
                                                  const int* __restrict__ labels,
                                                  const float* __restrict__ outv,
                                                  const float* __restrict__ rmp,
                                                  const float* __restrict__ rhp,
                                                  float* __restrict__ scal, int D) {
    int tid = threadIdx.x;
    int wave = tid >> 6, lane = tid & 63;
    __shared__ float ac[8];
    if (tid < 8) ac[tid] = 0.f;
    __syncthreads();
    float rm = rmp[0], rh = rhp[0];
    const float4* sm4 = (const float4*)s_m;
    for (int it = 0; it < 8; ++it) {
        int i = blockIdx.x * 32 + it * 4 + wave;
        const float4* row = (const float4*)(emb + (size_t)i * D);
        float q = 0.f, sd = 0.f;
#pragma unroll
        for (int j = 0; j < 4; ++j) {
            float4 e = row[lane * 4 + j];
            float4 s = sm4[lane * 4 + j];
            q += e.x * s.x + e.y * s.y + e.z * s.z + e.w * s.w;
            sd += e.x * e.x + e.y * e.y + e.z * e.z + e.w * e.w;
        }
#pragma unroll
        for (int m = 1; m <= 32; m <<= 1) {
            q += __shfl_xor(q, m, 64);
            sd += __shfl_xor(sd, m, 64);
        }
        if (lane == 0) {
            float LP = Sp[i];
            float eS = __expf(LP - INV_T);
            float lse = INV_T + __logf(sumexp[i] + eS);
            bool mach = (labels[i] == 0);
            float pos = (q - (mach ? sd : 0.f)) * INV_T + LP;
            float d = outv[5 + i];
            atomicAdd(&ac[2], eS);
            if (mach) {
                atomicAdd(&ac[4], lse);
                atomicAdd(&ac[5], pos);
                atomicAdd(&ac[3], LP);
                float x = d - rm;
                if (x > 0.f) atomicAdd(&ac[0], x * x);
            } else {
                float x = rh - d;
                if (x > 0.f) atomicAdd(&ac[1], x * x);
            }
        }
    }
    __syncthreads();
    if (tid < 8) atomicAdd(&scal[tid], ac[tid]);
}

// ---- combine scalars ----
__global__ void k_final(const float* __restrict__ scal, const int* __restrict__ cnt,
                        float* __restrict__ out) {
    if (threadIdx.x == 0) {
        int nm = cnt[0], nh = cnt[1];
        float nmf = (float)(nm > 1 ? nm : 1);
        float nhf = (float)(nh > 1 ? nh : 1);
        float loss_m = scal[0] / nmf;
        float loss_h = scal[1] / nhf;
        float loss_shell = loss_m + loss_h;
        float lse_p = INV_T + __logf(scal[2]);
        float proto = lse_p - scal[3] / nmf;
        float con = scal[4] - scal[5] / nmf;
        int denom = (nm + 1 > 1) ? nm + 1 : 1;
        float lc = (con + proto) / (float)denom;
        if (!(nm > 0 && nh > 0)) lc = 0.f;
        out[0] = loss_shell + lc;
        out[1] = loss_shell;
        out[2] = loss_m;
        out[3] = loss_h;
        out[4] = lc;
    }
}

extern "C" void kernel_launch(void* const* d_in, const int* in_sizes, int n_in,
                              void* d_out, int out_size, void* d_ws, size_t ws_size,
                              hipStream_t stream) {
    const float* emb = (const float*)d_in[0];
    const float* center = (const float*)d_in[1];
    const float* rmp = (const float*)d_in[2];
    const float* rhp = (const float*)d_in[3];
    const int* labels = (const int*)d_in[4];
    float* out = (float*)d_out;
    const int B = in_sizes[4];
    const int D = in_sizes[1];

    size_t bfBytes = (size_t)B * D * 2;
    size_t auxBytes = (size_t)B * 4 + (size_t)D * 4 + 256 + (size_t)B * 4;
    bool pre = ws_size >= bfBytes + auxBytes;
    size_t Z0 = pre ? bfBytes : 0;

    char* ws = (char*)d_ws;
    unsigned short* embB = (unsigned short*)ws;
    float* sumexp = (float*)(ws + Z0);
    float* s_m = (float*)(ws + Z0 + (size_t)B * 4);
    float* scal = (float*)(ws + Z0 + (size_t)B * 4 + (size_t)D * 4);
    int* cnt = (int*)(scal + 8);
    float* Sp = (float*)(ws + Z0 + (size_t)B * 4 + (size_t)D * 4 + 256);

    hipMemsetAsync(ws + Z0, 0, (size_t)B * 4 + (size_t)D * 4 + 256, stream);

    k_prep<<<B, D / 4, 0, stream>>>(emb, center, labels, pre ? embB : nullptr, out, Sp, cnt, D);
    k_colsum<<<B / 32, D / 4, 0, stream>>>(emb, labels, s_m, D);

    int nRT = B / 256;
    int nBlocks = nRT * (nRT + 1);
    if (pre) k_sumexp<true><<<nBlocks, 256, 0, stream>>>(embB, nullptr, sumexp, D, nRT);
    else     k_sumexp<false><<<nBlocks, 256, 0, stream>>>(nullptr, emb, sumexp, D, nRT);

    k_finalize<<<B / 32, 256, 0, stream>>>(emb, s_m, Sp, sumexp, labels, out, rmp, rhp, scal, D);
    k_final<<<1, 64, 0, stream>>>(scal, cnt, out);
}